// Round 7
// baseline (2361.980 us; speedup 1.0000x reference)
//
#include <hip/hip_runtime.h>
#include <math.h>

#define DEV static __device__ __forceinline__

constexpr int S_ = 2048;
constexpr int D_ = 1024;
constexpr int H_ = 16;

typedef __attribute__((ext_vector_type(8))) short bf16x8;
typedef __attribute__((ext_vector_type(4))) float f32x4;
typedef __attribute__((ext_vector_type(8))) short s16x8;

DEV unsigned short f2bf(float x) {
    union { float f; unsigned u; } c; c.f = x;
    const unsigned r = (c.u + 0x7FFFu + ((c.u >> 16) & 1u)) >> 16;
    return (unsigned short)r;
}
DEV float bf2f(unsigned short u) {
    union { unsigned u; float f; } c; c.u = ((unsigned)u) << 16;
    return c.f;
}

// bijective XCD swizzle (nwg % 8 == 0 for every grid we launch)
DEV int xcd_swizzle(int wg, int nwg) {
    const int nx = nwg >> 3;
    return (wg & 7) * nx + (wg >> 3);
}

DEV float blockReduceSum(float v) {
    #pragma unroll
    for (int m = 1; m < 64; m <<= 1) v += __shfl_xor(v, m, 64);
    __shared__ float wsr[4];
    const int lane = threadIdx.x & 63, wid = threadIdx.x >> 6;
    if (lane == 0) wsr[wid] = v;
    __syncthreads();
    v = wsr[0] + wsr[1] + wsr[2] + wsr[3];
    __syncthreads();
    return v;
}

// ---------------- LayerNorm (fp32 in, fp32 or bf16 out) ----------------
template<int BF16OUT>
__global__ __launch_bounds__(256)
void ln_k(const float* __restrict__ x, const float* __restrict__ g,
          const float* __restrict__ b, void* __restrict__ o)
{
    const int m = blockIdx.x, tid = threadIdx.x;
    const float* xr = x + (size_t)m * D_;
    const float4 xv = *(const float4*)(xr + tid * 4);
    float s = xv.x + xv.y + xv.z + xv.w;
    s = blockReduceSum(s);
    const float mu = s * (1.0f / 1024.0f);
    const float d0 = xv.x - mu, d1 = xv.y - mu, d2 = xv.z - mu, d3 = xv.w - mu;
    float sq = d0 * d0 + d1 * d1 + d2 * d2 + d3 * d3;
    sq = blockReduceSum(sq);
    const float rstd = rsqrtf(sq * (1.0f / 1024.0f) + 1e-5f);
    const float4 gv = *(const float4*)(g + tid * 4);
    const float4 bv = *(const float4*)(b + tid * 4);
    const float o0 = d0 * rstd * gv.x + bv.x;
    const float o1 = d1 * rstd * gv.y + bv.y;
    const float o2 = d2 * rstd * gv.z + bv.z;
    const float o3 = d3 * rstd * gv.w + bv.w;
    if constexpr (BF16OUT) {
        unsigned short* ob = (unsigned short*)o + (size_t)m * D_ + tid * 4;
        *(ushort4*)ob = make_ushort4(f2bf(o0), f2bf(o1), f2bf(o2), f2bf(o3));
    } else {
        *(float4*)((float*)o + (size_t)m * D_ + tid * 4) = make_float4(o0, o1, o2, o3);
    }
}

// ---------------- fp32 GEMM v3: C[M,N] = A[M,K] * B[N,K]^T -------------------
// 128x128 tile, 256 threads, 8x8/thread, BK=32, reg-prefetch, XCD swizzle.
// Per-output accumulation order: k = 0..Kd-1 strictly sequential (FROZEN).
// MODE 0: +bias, permuted store to [B,H,S,64].
// MODE 2: score write:  C  = extra[2m]*acc
// MODE 3: score accum:  C += extra[2m]*acc
template<int MODE>
__global__ __launch_bounds__(256)
void gemm32_k(const float* __restrict__ A, const float* __restrict__ Bw,
              const float* __restrict__ bias, const float* __restrict__ extra,
              float* __restrict__ Cout, int M, int N, int Kd)
{
    __shared__ __align__(16) float As[32][132];
    __shared__ __align__(16) float Bs[32][132];
    const int tid = threadIdx.x;
    const int tx = tid & 15, ty = tid >> 4;
    const int swz = xcd_swizzle(blockIdx.y * gridDim.x + blockIdx.x,
                                gridDim.x * gridDim.y);
    const int bx = swz % gridDim.x, by = swz / gridDim.x;
    const int row0 = by * 128, col0 = bx * 128;
    const int lr = tid & 127, lk = (tid >> 7) * 16;
    const float* Ap = A + (size_t)(row0 + lr) * Kd + lk;
    const float* Bp = Bw + (size_t)(col0 + lr) * Kd + lk;
    float acc[8][8] = {};

    float4 ar[4], br[4];
    #pragma unroll
    for (int jj = 0; jj < 4; ++jj) {
        ar[jj] = *(const float4*)(Ap + jj * 4);
        br[jj] = *(const float4*)(Bp + jj * 4);
    }

    for (int k0 = 0; k0 < Kd; k0 += 32) {
        __syncthreads();
        #pragma unroll
        for (int jj = 0; jj < 4; ++jj) {
            As[lk + jj * 4 + 0][lr] = ar[jj].x;
            As[lk + jj * 4 + 1][lr] = ar[jj].y;
            As[lk + jj * 4 + 2][lr] = ar[jj].z;
            As[lk + jj * 4 + 3][lr] = ar[jj].w;
            Bs[lk + jj * 4 + 0][lr] = br[jj].x;
            Bs[lk + jj * 4 + 1][lr] = br[jj].y;
            Bs[lk + jj * 4 + 2][lr] = br[jj].z;
            Bs[lk + jj * 4 + 3][lr] = br[jj].w;
        }
        __syncthreads();
        if (k0 + 32 < Kd) {
            #pragma unroll
            for (int jj = 0; jj < 4; ++jj) {
                ar[jj] = *(const float4*)(Ap + k0 + 32 + jj * 4);
                br[jj] = *(const float4*)(Bp + k0 + 32 + jj * 4);
            }
        }
        #pragma unroll
        for (int kk = 0; kk < 32; ++kk) {
            float av[8], bv[8];
            *(float4*)&av[0] = *(const float4*)&As[kk][ty * 8];
            *(float4*)&av[4] = *(const float4*)&As[kk][ty * 8 + 4];
            *(float4*)&bv[0] = *(const float4*)&Bs[kk][tx * 8];
            *(float4*)&bv[4] = *(const float4*)&Bs[kk][tx * 8 + 4];
            #pragma unroll
            for (int r = 0; r < 8; ++r)
                #pragma unroll
                for (int c = 0; c < 8; ++c)
                    acc[r][c] = fmaf(av[r], bv[c], acc[r][c]);
        }
    }

    const int gr0 = row0 + ty * 8, gc0 = col0 + tx * 8;
    if constexpr (MODE == 0) {
        const int hh = gc0 >> 6, dh = gc0 & 63;
        const float4 bias0 = *(const float4*)(bias + gc0);
        const float4 bias1 = *(const float4*)(bias + gc0 + 4);
        #pragma unroll
        for (int r = 0; r < 8; ++r) {
            const int m = gr0 + r;
            const int bb = m >> 11, s = m & (S_ - 1);
            float* dst = Cout + (((size_t)(bb * H_ + hh) * S_ + s) * 64 + dh);
            *(float4*)dst = make_float4(acc[r][0] + bias0.x, acc[r][1] + bias0.y,
                                        acc[r][2] + bias0.z, acc[r][3] + bias0.w);
            *(float4*)(dst + 4) = make_float4(acc[r][4] + bias1.x, acc[r][5] + bias1.y,
                                              acc[r][6] + bias1.z, acc[r][7] + bias1.w);
        }
    } else if constexpr (MODE == 2) {
        #pragma unroll
        for (int r = 0; r < 8; ++r) {
            const float rs = extra[2 * (gr0 + r)];
            float* dst = Cout + (size_t)(gr0 + r) * N + gc0;
            *(float4*)dst = make_float4(rs * acc[r][0], rs * acc[r][1],
                                        rs * acc[r][2], rs * acc[r][3]);
            *(float4*)(dst + 4) = make_float4(rs * acc[r][4], rs * acc[r][5],
                                              rs * acc[r][6], rs * acc[r][7]);
        }
    } else if constexpr (MODE == 3) {
        #pragma unroll
        for (int r = 0; r < 8; ++r) {
            const float rs = extra[2 * (gr0 + r)];
            float* dst = Cout + (size_t)(gr0 + r) * N + gc0;
            const float4 c0 = *(const float4*)dst;
            const float4 c1 = *(const float4*)(dst + 4);
            *(float4*)dst = make_float4(c0.x + rs * acc[r][0], c0.y + rs * acc[r][1],
                                        c0.z + rs * acc[r][2], c0.w + rs * acc[r][3]);
            *(float4*)(dst + 4) = make_float4(c1.x + rs * acc[r][4], c1.y + rs * acc[r][5],
                                              c1.z + rs * acc[r][6], c1.w + rs * acc[r][7]);
        }
    }
}

// ---------------- flash attention v5 (fp32) ----------------------------------
// 128q x 64kv tile, 256 threads, 8q x 4kv per thread.
// Per-row softmax identical to v2/v3/v4 (4 cols/lane, 16-lane butterfly).
// Per-element S, P, acc accumulation orders FROZEN (d- and j-sequential).
__global__ __launch_bounds__(256)
void attn5_k(const float* __restrict__ q, const float* __restrict__ k,
             const float* __restrict__ v, float* __restrict__ ctx)
{
    __shared__ __align__(16) float Qs[64][132];  // [d][i], 128 q rows
    __shared__ __align__(16) float Ks[64][68];   // [d][j]
    __shared__ __align__(16) float Vs[64][68];   // [j][d]
    __shared__ __align__(16) float Ps[128][68];  // [i][j]
    const int tid = threadIdx.x;
    const int tx = tid & 15, ty = tid >> 4;      // ty 0..15 (8 rows each)
    const int bh = blockIdx.y;
    const int q0 = blockIdx.x * 128;
    const float* qb = q + (size_t)bh * S_ * 64;
    const float* kb = k + (size_t)bh * S_ * 64;
    const float* vb = v + (size_t)bh * S_ * 64;

    const int j = tid & 63, dc = (tid >> 6) * 16;

    {   // Q tile (128 rows) -> LDS transposed [d][i]; 2 threads per row
        const int qi = tid >> 1, qdc = (tid & 1) * 32;
        const float* src = qb + (size_t)(q0 + qi) * 64 + qdc;
        #pragma unroll
        for (int u = 0; u < 8; ++u) {
            const float4 t = *(const float4*)(src + u * 4);
            Qs[qdc + u * 4 + 0][qi] = t.x;
            Qs[qdc + u * 4 + 1][qi] = t.y;
            Qs[qdc + u * 4 + 2][qi] = t.z;
            Qs[qdc + u * 4 + 3][qi] = t.w;
        }
    }

    // prologue: prefetch tile 0's K/V into registers
    float4 kr0, kr1, kr2, kr3, vr0, vr1, vr2, vr3;
    {
        const float* ks = kb + (size_t)j * 64 + dc;
        const float* vs = vb + (size_t)j * 64 + dc;
        kr0 = *(const float4*)(ks + 0);  kr1 = *(const float4*)(ks + 4);
        kr2 = *(const float4*)(ks + 8);  kr3 = *(const float4*)(ks + 12);
        vr0 = *(const float4*)(vs + 0);  vr1 = *(const float4*)(vs + 4);
        vr2 = *(const float4*)(vs + 8);  vr3 = *(const float4*)(vs + 12);
    }

    float mrow[8], lrow[8];
    #pragma unroll
    for (int r = 0; r < 8; ++r) { mrow[r] = -INFINITY; lrow[r] = 0.f; }
    float acc[8][4] = {};

    for (int kt = 0; kt < S_; kt += 64) {
        __syncthreads();   // prev tile's PV reads of Ps/Vs done; Q write covered
        // stage K (transposed) + V (row-major) from regs
        Ks[dc + 0][j] = kr0.x;  Ks[dc + 1][j] = kr0.y;  Ks[dc + 2][j] = kr0.z;  Ks[dc + 3][j] = kr0.w;
        Ks[dc + 4][j] = kr1.x;  Ks[dc + 5][j] = kr1.y;  Ks[dc + 6][j] = kr1.z;  Ks[dc + 7][j] = kr1.w;
        Ks[dc + 8][j] = kr2.x;  Ks[dc + 9][j] = kr2.y;  Ks[dc + 10][j] = kr2.z; Ks[dc + 11][j] = kr2.w;
        Ks[dc + 12][j] = kr3.x; Ks[dc + 13][j] = kr3.y; Ks[dc + 14][j] = kr3.z; Ks[dc + 15][j] = kr3.w;
        *(float4*)&Vs[j][dc + 0]  = vr0;
        *(float4*)&Vs[j][dc + 4]  = vr1;
        *(float4*)&Vs[j][dc + 8]  = vr2;
        *(float4*)&Vs[j][dc + 12] = vr3;
        __syncthreads();

        if (kt + 64 < S_) {   // issue next tile's loads; latency hides under compute
            const float* ks = kb + (size_t)(kt + 64 + j) * 64 + dc;
            const float* vs = vb + (size_t)(kt + 64 + j) * 64 + dc;
            kr0 = *(const float4*)(ks + 0);  kr1 = *(const float4*)(ks + 4);
            kr2 = *(const float4*)(ks + 8);  kr3 = *(const float4*)(ks + 12);
            vr0 = *(const float4*)(vs + 0);  vr1 = *(const float4*)(vs + 4);
            vr2 = *(const float4*)(vs + 8);  vr3 = *(const float4*)(vs + 12);
        }

        float s[8][4] = {};
        #pragma unroll 8
        for (int d = 0; d < 64; ++d) {
            const float4 qa = *(const float4*)&Qs[d][ty * 8];
            const float4 qc = *(const float4*)&Qs[d][ty * 8 + 4];
            const float4 k4 = *(const float4*)&Ks[d][tx * 4];
            s[0][0] = fmaf(qa.x, k4.x, s[0][0]); s[0][1] = fmaf(qa.x, k4.y, s[0][1]);
            s[0][2] = fmaf(qa.x, k4.z, s[0][2]); s[0][3] = fmaf(qa.x, k4.w, s[0][3]);
            s[1][0] = fmaf(qa.y, k4.x, s[1][0]); s[1][1] = fmaf(qa.y, k4.y, s[1][1]);
            s[1][2] = fmaf(qa.y, k4.z, s[1][2]); s[1][3] = fmaf(qa.y, k4.w, s[1][3]);
            s[2][0] = fmaf(qa.z, k4.x, s[2][0]); s[2][1] = fmaf(qa.z, k4.y, s[2][1]);
            s[2][2] = fmaf(qa.z, k4.z, s[2][2]); s[2][3] = fmaf(qa.z, k4.w, s[2][3]);
            s[3][0] = fmaf(qa.w, k4.x, s[3][0]); s[3][1] = fmaf(qa.w, k4.y, s[3][1]);
            s[3][2] = fmaf(qa.w, k4.z, s[3][2]); s[3][3] = fmaf(qa.w, k4.w, s[3][3]);
            s[4][0] = fmaf(qc.x, k4.x, s[4][0]); s[4][1] = fmaf(qc.x, k4.y, s[4][1]);
            s[4][2] = fmaf(qc.x, k4.z, s[4][2]); s[4][3] = fmaf(qc.x, k4.w, s[4][3]);
            s[5][0] = fmaf(qc.y, k4.x, s[5][0]); s[5][1] = fmaf(qc.y, k4.y, s[5][1]);
            s[5][2] = fmaf(qc.y, k4.z, s[5][2]); s[5][3] = fmaf(qc.y, k4.w, s[5][3]);
            s[6][0] = fmaf(qc.z, k4.x, s[6][0]); s[6][1] = fmaf(qc.z, k4.y, s[6][1]);
            s[6][2] = fmaf(qc.z, k4.z, s[6][2]); s[6][3] = fmaf(qc.z, k4.w, s[6][3]);
            s[7][0] = fmaf(qc.w, k4.x, s[7][0]); s[7][1] = fmaf(qc.w, k4.y, s[7][1]);
            s[7][2] = fmaf(qc.w, k4.z, s[7][2]); s[7][3] = fmaf(qc.w, k4.w, s[7][3]);
        }

        #pragma unroll
        for (int r = 0; r < 8; ++r) {
            float s0 = s[r][0] * 0.125f, s1 = s[r][1] * 0.125f;
            float s2 = s[r][2] * 0.125f, s3 = s[r][3] * 0.125f;
            float rm = fmaxf(fmaxf(s0, s1), fmaxf(s2, s3));
            #pragma unroll
            for (int sh = 1; sh < 16; sh <<= 1) rm = fmaxf(rm, __shfl_xor(rm, sh, 64));
            const float mn = fmaxf(mrow[r], rm);
            const float p0 = expf(s0 - mn), p1 = expf(s1 - mn);
            const float p2 = expf(s2 - mn), p3 = expf(s3 - mn);
            float rs = p0 + p1 + p2 + p3;
            #pragma unroll
            for (int sh = 1; sh < 16; sh <<= 1) rs += __shfl_xor(rs, sh, 64);
            const float esc = expf(mrow[r] - mn);
            lrow[r] = lrow[r] * esc + rs;
            mrow[r] = mn;
            acc[r][0] *= esc; acc[r][1] *= esc; acc[r][2] *= esc; acc[r][3] *= esc;
            *(float4*)&Ps[ty * 8 + r][tx * 4] = make_float4(p0, p1, p2, p3);
        }
        __syncthreads();   // P visible to all threads before PV

        #pragma unroll 4
        for (int jb = 0; jb < 16; ++jb) {
            const float4 v0 = *(const float4*)&Vs[jb * 4 + 0][tx * 4];
            const float4 v1 = *(const float4*)&Vs[jb * 4 + 1][tx * 4];
            const float4 v2 = *(const float4*)&Vs[jb * 4 + 2][tx * 4];
            const float4 v3 = *(const float4*)&Vs[jb * 4 + 3][tx * 4];
            #pragma unroll
            for (int r = 0; r < 8; ++r) {
                const float4 p4 = *(const float4*)&Ps[ty * 8 + r][jb * 4];
                acc[r][0] = fmaf(p4.x, v0.x, acc[r][0]); acc[r][1] = fmaf(p4.x, v0.y, acc[r][1]);
                acc[r][2] = fmaf(p4.x, v0.z, acc[r][2]); acc[r][3] = fmaf(p4.x, v0.w, acc[r][3]);
                acc[r][0] = fmaf(p4.y, v1.x, acc[r][0]); acc[r][1] = fmaf(p4.y, v1.y, acc[r][1]);
                acc[r][2] = fmaf(p4.y, v1.z, acc[r][2]); acc[r][3] = fmaf(p4.y, v1.w, acc[r][3]);
                acc[r][0] = fmaf(p4.z, v2.x, acc[r][0]); acc[r][1] = fmaf(p4.z, v2.y, acc[r][1]);
                acc[r][2] = fmaf(p4.z, v2.z, acc[r][2]); acc[r][3] = fmaf(p4.z, v2.w, acc[r][3]);
                acc[r][0] = fmaf(p4.w, v3.x, acc[r][0]); acc[r][1] = fmaf(p4.w, v3.y, acc[r][1]);
                acc[r][2] = fmaf(p4.w, v3.z, acc[r][2]); acc[r][3] = fmaf(p4.w, v3.w, acc[r][3]);
            }
        }
    }

    const int bb = bh >> 4, hh = bh & 15;
    #pragma unroll
    for (int r = 0; r < 8; ++r) {
        const float inv = 1.0f / lrow[r];
        *(float4*)(ctx + (size_t)(bb * S_ + q0 + ty * 8 + r) * D_ + hh * 64 + tx * 4) =
            make_float4(acc[r][0] * inv, acc[r][1] * inv, acc[r][2] * inv, acc[r][3] * inv);
    }
}

// ---------------- path gate ----------------
__global__ __launch_bounds__(256)
void pathw_k(const float* __restrict__ normed, const float* __restrict__ ctx,
             const float* __restrict__ wp, const float* __restrict__ bp,
             float* __restrict__ pw)
{
    const int m = blockIdx.x, tid = threadIdx.x;
    const float4 n4 = *(const float4*)(normed + (size_t)m * D_ + tid * 4);
    const float4 c4 = *(const float4*)(ctx + (size_t)m * D_ + tid * 4);
    const float4 w0n = *(const float4*)(wp + tid * 4);
    const float4 w0c = *(const float4*)(wp + 1024 + tid * 4);
    const float4 w1n = *(const float4*)(wp + 2048 + tid * 4);
    const float4 w1c = *(const float4*)(wp + 3072 + tid * 4);
    float p0 = n4.x * w0n.x + n4.y * w0n.y + n4.z * w0n.z + n4.w * w0n.w
             + c4.x * w0c.x + c4.y * w0c.y + c4.z * w0c.z + c4.w * w0c.w;
    float p1 = n4.x * w1n.x + n4.y * w1n.y + n4.z * w1n.z + n4.w * w1n.w
             + c4.x * w1c.x + c4.y * w1c.y + c4.z * w1c.z + c4.w * w1c.w;
    p0 = blockReduceSum(p0);
    p1 = blockReduceSum(p1);
    if (tid == 0) {
        const float l0 = p0 + bp[0], l1 = p1 + bp[1];
        const float mx = fmaxf(l0, l1);
        const float e0 = expf(l0 - mx), e1 = expf(l1 - mx);
        const float inv = 1.0f / (e0 + e1);
        pw[2 * m] = e0 * inv;
        pw[2 * m + 1] = e1 * inv;
    }
}

// ---------------- neuron top-16 + router output ------------------------------
__global__ __launch_bounds__(256)
void topk_router_k(const float* __restrict__ scores, const float* __restrict__ neurons,
                   const float* __restrict__ x, float* __restrict__ idx_out,
                   float* __restrict__ x1, float* __restrict__ router)
{
    __shared__ __align__(16) float sc[4096];
    __shared__ unsigned long long wred[4];
    __shared__ int ki_s[16];
    __shared__ float kv_s[16];
    __shared__ float kw_s[16];
    const int m = blockIdx.x, tid = threadIdx.x;
    const float* srow = scores + (size_t)m * 4096;
    for (int i = tid; i < 1024; i += 256)
        *(float4*)&sc[i * 4] = *(const float4*)(srow + i * 4);
    __syncthreads();

    for (int t = 0; t < 16; ++t) {
        unsigned long long best = 0ull;
        for (int i = tid; i < 4096; i += 256) {
            unsigned u = __float_as_uint(sc[i]);
            u = (u & 0x80000000u) ? ~u : (u | 0x80000000u);
            const unsigned long long key =
                ((unsigned long long)u << 32) | (unsigned long long)(0xFFFFFFFFu - (unsigned)i);
            if (key > best) best = key;
        }
        #pragma unroll
        for (int sh = 1; sh < 64; sh <<= 1) {
            const unsigned long long o = __shfl_xor(best, sh, 64);
            if (o > best) best = o;
        }
        if ((tid & 63) == 0) wred[tid >> 6] = best;
        __syncthreads();
        if (tid == 0) {
            unsigned long long bb = wred[0];
            if (wred[1] > bb) bb = wred[1];
            if (wred[2] > bb) bb = wred[2];
            if (wred[3] > bb) bb = wred[3];
            const int idx = (int)(0xFFFFFFFFu - (unsigned)(bb & 0xFFFFFFFFull));
            ki_s[t] = idx;
            kv_s[t] = sc[idx];
            sc[idx] = -INFINITY;
        }
        __syncthreads();
    }

    if (tid == 0) {
        const float mx = kv_s[0];
        float es[16], sum = 0.f;
        #pragma unroll
        for (int t = 0; t < 16; ++t) { es[t] = expf(kv_s[t] - mx); sum += es[t]; }
        const float inv = 1.0f / sum;
        #pragma unroll
        for (int t = 0; t < 16; ++t) kw_s[t] = es[t] * inv;
    }
    __syncthreads();

    if (tid < 16) idx_out[(size_t)m * 16 + tid] = (float)ki_s[tid];

    float4 r = make_float4(0.f, 0.f, 0.f, 0.f);
    #pragma unroll
    for (int t = 0; t < 16; ++t) {
        const float w = kw_s[t];
        const float4 nv = *(const float4*)(neurons + (size_t)ki_s[t] * D_ + tid * 4);
        r.x = fmaf(w, nv.x, r.x); r.y = fmaf(w, nv.y, r.y);
        r.z = fmaf(w, nv.z, r.z); r.w = fmaf(w, nv.w, r.w);
    }
    const float4 xv = *(const float4*)(x + (size_t)m * D_ + tid * 4);
    *(float4*)(router + (size_t)m * D_ + tid * 4) = r;
    *(float4*)(x1 + (size_t)m * D_ + tid * 4) =
        make_float4(xv.x + r.x, xv.y + r.y, xv.z + r.z, xv.w + r.w);
}

// ---------------- pattern top-8 + gate mix (bf16 gate out) -------------------
__global__ __launch_bounds__(256)
void pattern_k(const float* __restrict__ router, const float* __restrict__ pq,
               const float* __restrict__ gates, unsigned short* __restrict__ gate_out)
{
    __shared__ __align__(16) float rr[1024];
    __shared__ float ps[64];
    __shared__ int pidx[8];
    __shared__ float pwt[8];
    const int m = blockIdx.x, tid = threadIdx.x;
    *(float4*)&rr[tid * 4] = *(const float4*)(router + (size_t)m * D_ + tid * 4);
    __syncthreads();

    const int p = tid >> 2, part = tid & 3;
    const float* pqr = pq + (size_t)p * D_ + part * 256;
    float sum = 0.f;
    for (int d = 0; d < 256; d += 4) {
        const float4 a = *(const float4*)(pqr + d);
        const float4 b = *(const float4*)&rr[part * 256 + d];
        sum += a.x * b.x + a.y * b.y + a.z * b.z + a.w * b.w;
    }
    sum += __shfl_xor(sum, 1, 64);
    sum += __shfl_xor(sum, 2, 64);
    if (part == 0) ps[p] = sum * (1.0f / 32.0f);
    __syncthreads();

    if (tid == 0) {
        float kv[8];
        for (int t = 0; t < 8; ++t) {
            float bv = -INFINITY; int bi = 0;
            for (int i = 0; i < 64; ++i) {
                const float vv = ps[i];
                if (vv > bv) { bv = vv; bi = i; }
            }
            kv[t] = bv; pidx[t] = bi; ps[bi] = -INFINITY;
        }
        const float mx = kv[0];
        float ee[8], tot = 0.f;
        for (int t = 0; t < 8; ++t) { ee[t] = expf(kv[t] - mx); tot += ee[t]; }
        for (int t = 0; t < 8; ++t) pwt[t] = ee[t] / tot;
    }
    __syncthreads();

    for (int f = tid * 4; f < 4096; f += 1024) {
        float4 g = make_float4(0.f, 0.f, 0.f, 0.f);
        #pragma unroll
        for (int t = 0; t < 8; ++t) {
            const float w = pwt[t];
            const float4 gv = *(const float4*)(gates + (size_t)pidx[t] * 4096 + f);
            g.x = fmaf(w, gv.x, g.x); g.y = fmaf(w, gv.y, g.y);
            g.z = fmaf(w, gv.z, g.z); g.w = fmaf(w, gv.w, g.w);
        }
        *(ushort4*)(gate_out + (size_t)m * 4096 + f) =
            make_ushort4(f2bf(g.x), f2bf(g.y), f2bf(g.z), f2bf(g.w));
    }
}

// ---------------- fp32 -> bf16 cast ----------------
__global__ __launch_bounds__(256)
void castbf_k(const float* __restrict__ in, unsigned short* __restrict__ out, int n)
{
    const int i = (blockIdx.x * 256 + threadIdx.x) * 8;
    if (i >= n) return;
    const float4 a = *(const float4*)(in + i);
    const float4 b = *(const float4*)(in + i + 4);
    *(ushort4*)(out + i) = make_ushort4(f2bf(a.x), f2bf(a.y), f2bf(a.z), f2bf(a.w));
    *(ushort4*)(out + i + 4) = make_ushort4(f2bf(b.x), f2bf(b.y), f2bf(b.z), f2bf(b.w));
}

// ---------------- bf16 MFMA GEMM: C[M,N] = A[M,K]*B[N,K]^T -------------------
// 128x128 tile, 4 waves (2x2), BK=32, 16x16x32 MFMA, reg-staged LDS, XCD swizzle.
// LDS row stride padded to 40 shorts (80B).
// EPI 0: h = bf16(gelu((acc+bias)*sigmoid(gate)))    EPI 1: out = acc+bias+resid (fp32)
template<int EPI>
__global__ __launch_bounds__(256)
void gemmbf_k(const unsigned short* __restrict__ A, const unsigned short* __restrict__ Bw,
              const float* __restrict__ bias, const unsigned short* __restrict__ gate,
              const float* resid, void* Cout, int M, int N, int Kd)
{
    constexpr int LSH = 40;
    __shared__ __align__(16) unsigned short Al[128 * LSH];
    __shared__ __align__(16) unsigned short Bl[128 * LSH];
    const int tid = threadIdx.x;
    const int lane = tid & 63;
    const int w = tid >> 6, wr = w >> 1, wc = w & 1;
    const int swz = xcd_swizzle(blockIdx.y * gridDim.x + blockIdx.x,
                                gridDim.x * gridDim.y);
    const int row0 = (swz / gridDim.x) * 128, col0 = (swz % gridDim.x) * 128;

    const int o0 = tid * 16, o1 = o0 + 4096;
    const int r0 = o0 >> 6, k0e = (o0 & 63) >> 1;
    const int r1 = o1 >> 6, k1e = (o1 & 63) >> 1;
    const int l0 = r0 * LSH + k0e, l1 = r1 * LSH + k1e;
    const unsigned short* Ap0 = A + (size_t)(row0 + r0) * Kd + k0e;
    const unsigned short* Ap1 = A + (size_t)(row0 + r1) * Kd + k1e;
    const unsigned short* Bp0 = Bw + (size_t)(col0 + r0) * Kd + k0e;
    const unsigned short* Bp1 = Bw + (size_t)(col0 + r1) * Kd + k1e;

    f32x4 acc[4][4];
    #pragma unroll
    for (int m = 0; m < 4; ++m)
        #pragma unroll
        for (int n = 0; n < 4; ++n)
            #pragma unroll
            for (int e = 0; e < 4; ++e) acc[m][n][e] = 0.f;

    s16x8 ra0 = *(const s16x8*)Ap0;
    s16x8 ra1 = *(const s16x8*)Ap1;
    s16x8 rb0 = *(const s16x8*)Bp0;
    s16x8 rb1 = *(const s16x8*)Bp1;

    const int fr = lane & 15, kg = (lane >> 4) * 8;
    const unsigned short* aBase = Al + ((wr * 64 + fr) * LSH + kg);
    const unsigned short* bBase = Bl + ((wc * 64 + fr) * LSH + kg);

    for (int k0 = 0; k0 < Kd; k0 += 32) {
        __syncthreads();
        *(s16x8*)(Al + l0) = ra0;
        *(s16x8*)(Al + l1) = ra1;
        *(s16x8*)(Bl + l0) = rb0;
        *(s16x8*)(Bl + l1) = rb1;
        __syncthreads();
        if (k0 + 32 < Kd) {
            ra0 = *(const s16x8*)(Ap0 + k0 + 32);
            ra1 = *(const s16x8*)(Ap1 + k0 + 32);
            rb0 = *(const s16x8*)(Bp0 + k0 + 32);
            rb1 = *(const s16x8*)(Bp1 + k0 + 32);
        }
        bf16x8 aF[4], bF[4];
        #pragma unroll
        for (int m = 0; m < 4; ++m) aF[m] = *(const bf16x8*)(aBase + m * 16 * LSH);
        #pragma unroll
        for (int n = 0; n < 4; ++n) bF[n] = *(const bf16x8*)(bBase + n * 16 * LSH);
        #pragma unroll
        for (int m = 0; m < 4; ++m)
            #pragma unroll
            for (int n = 0; n < 4; ++n)
                acc[m][n] = __builtin_amdgcn_mfma_f32_16x16x32_bf16(aF[m], bF[n], acc[m][n], 0, 0, 0);
    }

    const int rbase = (lane >> 4) * 4;
    #pragma unroll
    for (int m = 0; m < 4; ++m) {
        #pragma unroll
        for (int n = 0; n < 4; ++n) {
            const int gcol = col0 + wc * 64 + n * 16 + (lane & 15);
            const int growb = row0 + wr * 64 + m * 16 + rbase;
            const float bc = bias[gcol];
            #pragma unroll
            for (int r = 0; r < 4; ++r) {
                const int grow = growb + r;
                const float vv = acc[m][n][r];
                if constexpr (EPI == 0) {
                    const float z = vv + bc;
                    const float gt = bf2f(gate[(size_t)grow * N + gcol]);
                    const float zz = z / (1.f + expf(-gt));
                    const float o = 0.5f * zz * (1.f + erff(zz * 0.70710678118654752440f));
                    ((unsigned short*)Cout)[(size_t)grow * N + gcol] = f2bf(o);
                } else {
                    ((float*)Cout)[(size_t)grow * N + gcol] =
                        vv + bc + resid[(size_t)grow * N + gcol];
                }
            }
        }
    }
}

// ---------------- launcher ----------------
extern "C" void kernel_launch(void* const* d_in, const int* in_sizes, int n_in,
                              void* d_out, int out_size, void* d_ws, size_t ws_size,
                              hipStream_t stream)
{
    const float* x      = (const float*)d_in[0];
    const float* neurons= (const float*)d_in[1];
    const float* wq = (const float*)d_in[2];  const float* bq = (const float*)d_in[3];
    const float* wk = (const float*)d_in[4];  const float* bk = (const float*)d_in[5];
    const float* wv = (const float*)d_in[6];  const float* bv = (const float*)d_in[7];
    const float* wp = (const float*)d_in[8];  const float* bp = (const float*)d_in[9];
    const float* pq = (const float*)d_in[10];
    const float* gates = (const float*)d_in[11];
    const float* w_up = (const float*)d_in[12];  const float* b_up = (const float*)d_in[13];
    const float* w_dn = (const float*)d_in[14];  const float* b_dn = (const float*)d_in[15];
    const float* ln1g = (const float*)d_in[16];  const float* ln1b = (const float*)d_in[17];
    const float* ln2g = (const float*)d_in[18];  const float* ln2b = (const float*)d_in[19];

    float* out0    = (float*)d_out;
    float* idx_out = out0 + (size_t)4096 * 1024;

    float* ws      = (float*)d_ws;
    float* scores  = ws;                 // 16,777,216 floats
    float* normed  = ws + 16777216;      //  4,194,304
    float* qb      = ws + 20971520;      //  4,194,304
    float* kb      = ws + 25165824;      //  4,194,304
    float* vb      = ws + 29360128;      //  4,194,304
    float* ctx     = ws + 33554432;      //  4,194,304
    float* router  = ws + 37748736;      //  4,194,304
    float* pw      = ws + 41943040;      //      8,192

    unsigned short* gate_bf   = (unsigned short*)qb;                  // qb+kb region
    unsigned short* h_bf      = (unsigned short*)scores;              // scores[0 .. 8.4M floats)
    unsigned short* normed2bf = (unsigned short*)(scores + 8388608);  // next 2.1M floats
    unsigned short* wup_bf    = (unsigned short*)router;              // router dead post-pattern
    unsigned short* wdn_bf    = wup_bf + 4194304;
    float* x1 = out0;

    const dim3 blk(256);

    ln_k<0><<<4096, blk, 0, stream>>>(x, ln1g, ln1b, normed);
    gemm32_k<0><<<dim3(8, 32), blk, 0, stream>>>(normed, wq, bq, nullptr, qb, 4096, 1024, 1024);
    gemm32_k<0><<<dim3(8, 32), blk, 0, stream>>>(normed, wk, bk, nullptr, kb, 4096, 1024, 1024);
    gemm32_k<0><<<dim3(8, 32), blk, 0, stream>>>(normed, wv, bv, nullptr, vb, 4096, 1024, 1024);
    attn5_k<<<dim3(16, 32), blk, 0, stream>>>(qb, kb, vb, ctx);
    pathw_k<<<4096, blk, 0, stream>>>(normed, ctx, wp, bp, pw);
    gemm32_k<2><<<dim3(32, 32), blk, 0, stream>>>(normed, neurons, nullptr, pw, scores, 4096, 4096, 1024);
    gemm32_k<3><<<dim3(32, 32), blk, 0, stream>>>(ctx, neurons, nullptr, pw + 1, scores, 4096, 4096, 1024);
    topk_router_k<<<4096, blk, 0, stream>>>(scores, neurons, x, idx_out, x1, router);
    ln_k<1><<<4096, blk, 0, stream>>>(x1, ln2g, ln2b, normed2bf);
    pattern_k<<<4096, blk, 0, stream>>>(router, pq, gates, gate_bf);
    castbf_k<<<2048, blk, 0, stream>>>(w_up, wup_bf, 4194304);
    castbf_k<<<2048, blk, 0, stream>>>(w_dn, wdn_bf, 4194304);
    gemmbf_k<0><<<dim3(32, 32), blk, 0, stream>>>(normed2bf, wup_bf, b_up, gate_bf, nullptr, h_bf, 4096, 4096, 1024);
    gemmbf_k<1><<<dim3(8, 32), blk, 0, stream>>>(h_bf, wdn_bf, b_dn, nullptr, x1, out0, 4096, 1024, 4096);
}

// Round 8
// 2023.403 us; speedup vs baseline: 1.1673x; 1.1673x over previous
//
#include <hip/hip_runtime.h>
#include <math.h>

#define DEV static __device__ __forceinline__

constexpr int S_ = 2048;
constexpr int D_ = 1024;
constexpr int H_ = 16;

typedef __attribute__((ext_vector_type(8))) short bf16x8;
typedef __attribute__((ext_vector_type(4))) float f32x4;
typedef __attribute__((ext_vector_type(8))) short s16x8;

DEV unsigned short f2bf(float x) {
    union { float f; unsigned u; } c; c.f = x;
    const unsigned r = (c.u + 0x7FFFu + ((c.u >> 16) & 1u)) >> 16;
    return (unsigned short)r;
}
DEV float bf2f(unsigned short u) {
    union { unsigned u; float f; } c; c.u = ((unsigned)u) << 16;
    return c.f;
}

// bijective XCD swizzle (nwg % 8 == 0 for every grid we launch)
DEV int xcd_swizzle(int wg, int nwg) {
    const int nx = nwg >> 3;
    return (wg & 7) * nx + (wg >> 3);
}

DEV float blockReduceSum(float v) {
    #pragma unroll
    for (int m = 1; m < 64; m <<= 1) v += __shfl_xor(v, m, 64);
    __shared__ float wsr[4];
    const int lane = threadIdx.x & 63, wid = threadIdx.x >> 6;
    if (lane == 0) wsr[wid] = v;
    __syncthreads();
    v = wsr[0] + wsr[1] + wsr[2] + wsr[3];
    __syncthreads();
    return v;
}

// ---------------- LayerNorm (ln1, fp32 out) ----------------
__global__ __launch_bounds__(256)
void ln_k(const float* __restrict__ x, const float* __restrict__ g,
          const float* __restrict__ b, float* __restrict__ o)
{
    const int m = blockIdx.x, tid = threadIdx.x;
    const float* xr = x + (size_t)m * D_;
    const float4 xv = *(const float4*)(xr + tid * 4);
    float s = xv.x + xv.y + xv.z + xv.w;
    s = blockReduceSum(s);
    const float mu = s * (1.0f / 1024.0f);
    const float d0 = xv.x - mu, d1 = xv.y - mu, d2 = xv.z - mu, d3 = xv.w - mu;
    float sq = d0 * d0 + d1 * d1 + d2 * d2 + d3 * d3;
    sq = blockReduceSum(sq);
    const float rstd = rsqrtf(sq * (1.0f / 1024.0f) + 1e-5f);
    const float4 gv = *(const float4*)(g + tid * 4);
    const float4 bv = *(const float4*)(b + tid * 4);
    *(float4*)(o + (size_t)m * D_ + tid * 4) =
        make_float4(d0 * rstd * gv.x + bv.x, d1 * rstd * gv.y + bv.y,
                    d2 * rstd * gv.z + bv.z, d3 * rstd * gv.w + bv.w);
}

// ---------------- merged QKV GEMM -------------------------------------------
// C = A @ W^T + bias, W in {wq,wk,wv} selected by column block; permuted store.
// Same tile/microkernel as gemm32_k -> per-element bits identical.
__global__ __launch_bounds__(256)
void gemmqkv_k(const float* __restrict__ A,
               const float* __restrict__ Bq, const float* __restrict__ Bk2,
               const float* __restrict__ Bv,
               const float* __restrict__ bq, const float* __restrict__ bk2,
               const float* __restrict__ bv, float* __restrict__ Cout)
{
    const int Kd = 1024;
    __shared__ __align__(16) float As[32][132];
    __shared__ __align__(16) float Bs[32][132];
    const int tid = threadIdx.x;
    const int tx = tid & 15, ty = tid >> 4;
    const int swz = xcd_swizzle(blockIdx.y * gridDim.x + blockIdx.x,
                                gridDim.x * gridDim.y);
    const int bx = swz % gridDim.x, by = swz / gridDim.x;
    const int row0 = by * 128, col0g = bx * 128;
    const int which = col0g >> 10;
    const float* Bw = (which == 0) ? Bq : ((which == 1) ? Bk2 : Bv);
    const float* bias = (which == 0) ? bq : ((which == 1) ? bk2 : bv);
    float* Cb = Cout + (size_t)which * 4194304;
    const int col0 = col0g & 1023;

    const int lr = tid & 127, lk = (tid >> 7) * 16;
    const float* Ap = A + (size_t)(row0 + lr) * Kd + lk;
    const float* Bp = Bw + (size_t)(col0 + lr) * Kd + lk;
    float acc[8][8] = {};

    float4 ar[4], br[4];
    #pragma unroll
    for (int jj = 0; jj < 4; ++jj) {
        ar[jj] = *(const float4*)(Ap + jj * 4);
        br[jj] = *(const float4*)(Bp + jj * 4);
    }

    for (int k0 = 0; k0 < Kd; k0 += 32) {
        __syncthreads();
        #pragma unroll
        for (int jj = 0; jj < 4; ++jj) {
            As[lk + jj * 4 + 0][lr] = ar[jj].x;
            As[lk + jj * 4 + 1][lr] = ar[jj].y;
            As[lk + jj * 4 + 2][lr] = ar[jj].z;
            As[lk + jj * 4 + 3][lr] = ar[jj].w;
            Bs[lk + jj * 4 + 0][lr] = br[jj].x;
            Bs[lk + jj * 4 + 1][lr] = br[jj].y;
            Bs[lk + jj * 4 + 2][lr] = br[jj].z;
            Bs[lk + jj * 4 + 3][lr] = br[jj].w;
        }
        __syncthreads();
        if (k0 + 32 < Kd) {
            #pragma unroll
            for (int jj = 0; jj < 4; ++jj) {
                ar[jj] = *(const float4*)(Ap + k0 + 32 + jj * 4);
                br[jj] = *(const float4*)(Bp + k0 + 32 + jj * 4);
            }
        }
        #pragma unroll
        for (int kk = 0; kk < 32; ++kk) {
            float av[8], bv2[8];
            *(float4*)&av[0] = *(const float4*)&As[kk][ty * 8];
            *(float4*)&av[4] = *(const float4*)&As[kk][ty * 8 + 4];
            *(float4*)&bv2[0] = *(const float4*)&Bs[kk][tx * 8];
            *(float4*)&bv2[4] = *(const float4*)&Bs[kk][tx * 8 + 4];
            #pragma unroll
            for (int r = 0; r < 8; ++r)
                #pragma unroll
                for (int c = 0; c < 8; ++c)
                    acc[r][c] = fmaf(av[r], bv2[c], acc[r][c]);
        }
    }

    const int gr0 = row0 + ty * 8, gc0 = col0 + tx * 8;
    const int hh = gc0 >> 6, dh = gc0 & 63;
    const float4 bias0 = *(const float4*)(bias + gc0);
    const float4 bias1 = *(const float4*)(bias + gc0 + 4);
    #pragma unroll
    for (int r = 0; r < 8; ++r) {
        const int m = gr0 + r;
        const int bb = m >> 11, s = m & (S_ - 1);
        float* dst = Cb + (((size_t)(bb * H_ + hh) * S_ + s) * 64 + dh);
        *(float4*)dst = make_float4(acc[r][0] + bias0.x, acc[r][1] + bias0.y,
                                    acc[r][2] + bias0.z, acc[r][3] + bias0.w);
        *(float4*)(dst + 4) = make_float4(acc[r][4] + bias1.x, acc[r][5] + bias1.y,
                                          acc[r][6] + bias1.z, acc[r][7] + bias1.w);
    }
}

// ---------------- fp32 score GEMM (frozen arithmetic) ------------------------
// MODE 2: C  = extra[2m]*acc      MODE 3: C += extra[2m]*acc
template<int MODE>
__global__ __launch_bounds__(256)
void gemm32_k(const float* __restrict__ A, const float* __restrict__ Bw,
              const float* __restrict__ bias, const float* __restrict__ extra,
              float* __restrict__ Cout, int M, int N, int Kd)
{
    __shared__ __align__(16) float As[32][132];
    __shared__ __align__(16) float Bs[32][132];
    const int tid = threadIdx.x;
    const int tx = tid & 15, ty = tid >> 4;
    const int swz = xcd_swizzle(blockIdx.y * gridDim.x + blockIdx.x,
                                gridDim.x * gridDim.y);
    const int bx = swz % gridDim.x, by = swz / gridDim.x;
    const int row0 = by * 128, col0 = bx * 128;
    const int lr = tid & 127, lk = (tid >> 7) * 16;
    const float* Ap = A + (size_t)(row0 + lr) * Kd + lk;
    const float* Bp = Bw + (size_t)(col0 + lr) * Kd + lk;
    float acc[8][8] = {};

    float4 ar[4], br[4];
    #pragma unroll
    for (int jj = 0; jj < 4; ++jj) {
        ar[jj] = *(const float4*)(Ap + jj * 4);
        br[jj] = *(const float4*)(Bp + jj * 4);
    }

    for (int k0 = 0; k0 < Kd; k0 += 32) {
        __syncthreads();
        #pragma unroll
        for (int jj = 0; jj < 4; ++jj) {
            As[lk + jj * 4 + 0][lr] = ar[jj].x;
            As[lk + jj * 4 + 1][lr] = ar[jj].y;
            As[lk + jj * 4 + 2][lr] = ar[jj].z;
            As[lk + jj * 4 + 3][lr] = ar[jj].w;
            Bs[lk + jj * 4 + 0][lr] = br[jj].x;
            Bs[lk + jj * 4 + 1][lr] = br[jj].y;
            Bs[lk + jj * 4 + 2][lr] = br[jj].z;
            Bs[lk + jj * 4 + 3][lr] = br[jj].w;
        }
        __syncthreads();
        if (k0 + 32 < Kd) {
            #pragma unroll
            for (int jj = 0; jj < 4; ++jj) {
                ar[jj] = *(const float4*)(Ap + k0 + 32 + jj * 4);
                br[jj] = *(const float4*)(Bp + k0 + 32 + jj * 4);
            }
        }
        #pragma unroll
        for (int kk = 0; kk < 32; ++kk) {
            float av[8], bv[8];
            *(float4*)&av[0] = *(const float4*)&As[kk][ty * 8];
            *(float4*)&av[4] = *(const float4*)&As[kk][ty * 8 + 4];
            *(float4*)&bv[0] = *(const float4*)&Bs[kk][tx * 8];
            *(float4*)&bv[4] = *(const float4*)&Bs[kk][tx * 8 + 4];
            #pragma unroll
            for (int r = 0; r < 8; ++r)
                #pragma unroll
                for (int c = 0; c < 8; ++c)
                    acc[r][c] = fmaf(av[r], bv[c], acc[r][c]);
        }
    }

    const int gr0 = row0 + ty * 8, gc0 = col0 + tx * 8;
    if constexpr (MODE == 2) {
        #pragma unroll
        for (int r = 0; r < 8; ++r) {
            const float rs = extra[2 * (gr0 + r)];
            float* dst = Cout + (size_t)(gr0 + r) * N + gc0;
            *(float4*)dst = make_float4(rs * acc[r][0], rs * acc[r][1],
                                        rs * acc[r][2], rs * acc[r][3]);
            *(float4*)(dst + 4) = make_float4(rs * acc[r][4], rs * acc[r][5],
                                              rs * acc[r][6], rs * acc[r][7]);
        }
    } else {
        #pragma unroll
        for (int r = 0; r < 8; ++r) {
            const float rs = extra[2 * (gr0 + r)];
            float* dst = Cout + (size_t)(gr0 + r) * N + gc0;
            const float4 c0 = *(const float4*)dst;
            const float4 c1 = *(const float4*)(dst + 4);
            *(float4*)dst = make_float4(c0.x + rs * acc[r][0], c0.y + rs * acc[r][1],
                                        c0.z + rs * acc[r][2], c0.w + rs * acc[r][3]);
            *(float4*)(dst + 4) = make_float4(c1.x + rs * acc[r][4], c1.y + rs * acc[r][5],
                                              c1.z + rs * acc[r][6], c1.w + rs * acc[r][7]);
        }
    }
}

// ---------------- flash attention v4 (fp32), 64q x 64kv, K/P LDS overlay -----
// LDS 52.2 KB -> 3 blocks/CU. (Round-6 source, verified.)
__global__ __launch_bounds__(256)
void attn4_k(const float* __restrict__ q, const float* __restrict__ k,
             const float* __restrict__ v, float* __restrict__ ctx)
{
    __shared__ __align__(16) float Qs[64][68];  // [d][i]
    __shared__ __align__(16) float KP[64][68];  // K as [d][j], then P as [i][j]
    __shared__ __align__(16) float Vs[64][68];  // [j][d]
    const int tid = threadIdx.x;
    const int tx = tid & 15, ty = tid >> 4;
    const int bh = blockIdx.y;
    const int q0 = blockIdx.x * 64;
    const float* qb = q + (size_t)bh * S_ * 64;
    const float* kb = k + (size_t)bh * S_ * 64;
    const float* vb = v + (size_t)bh * S_ * 64;

    const int j = tid & 63, dc = (tid >> 6) * 16;

    {   // Q tile -> LDS, transposed to [d][i]
        const float* src = qb + (size_t)(q0 + j) * 64 + dc;
        const float4 t0 = *(const float4*)(src + 0);
        const float4 t1 = *(const float4*)(src + 4);
        const float4 t2 = *(const float4*)(src + 8);
        const float4 t3 = *(const float4*)(src + 12);
        Qs[dc + 0][j] = t0.x;  Qs[dc + 1][j] = t0.y;  Qs[dc + 2][j] = t0.z;  Qs[dc + 3][j] = t0.w;
        Qs[dc + 4][j] = t1.x;  Qs[dc + 5][j] = t1.y;  Qs[dc + 6][j] = t1.z;  Qs[dc + 7][j] = t1.w;
        Qs[dc + 8][j] = t2.x;  Qs[dc + 9][j] = t2.y;  Qs[dc + 10][j] = t2.z; Qs[dc + 11][j] = t2.w;
        Qs[dc + 12][j] = t3.x; Qs[dc + 13][j] = t3.y; Qs[dc + 14][j] = t3.z; Qs[dc + 15][j] = t3.w;
    }

    float4 kr0, kr1, kr2, kr3, vr0, vr1, vr2, vr3;
    {
        const float* ks = kb + (size_t)j * 64 + dc;
        const float* vs = vb + (size_t)j * 64 + dc;
        kr0 = *(const float4*)(ks + 0);  kr1 = *(const float4*)(ks + 4);
        kr2 = *(const float4*)(ks + 8);  kr3 = *(const float4*)(ks + 12);
        vr0 = *(const float4*)(vs + 0);  vr1 = *(const float4*)(vs + 4);
        vr2 = *(const float4*)(vs + 8);  vr3 = *(const float4*)(vs + 12);
    }

    float mrow[4] = {-INFINITY, -INFINITY, -INFINITY, -INFINITY};
    float lrow[4] = {0.f, 0.f, 0.f, 0.f};
    float acc[4][4] = {};

    for (int kt = 0; kt < S_; kt += 64) {
        __syncthreads();
        KP[dc + 0][j] = kr0.x;  KP[dc + 1][j] = kr0.y;  KP[dc + 2][j] = kr0.z;  KP[dc + 3][j] = kr0.w;
        KP[dc + 4][j] = kr1.x;  KP[dc + 5][j] = kr1.y;  KP[dc + 6][j] = kr1.z;  KP[dc + 7][j] = kr1.w;
        KP[dc + 8][j] = kr2.x;  KP[dc + 9][j] = kr2.y;  KP[dc + 10][j] = kr2.z; KP[dc + 11][j] = kr2.w;
        KP[dc + 12][j] = kr3.x; KP[dc + 13][j] = kr3.y; KP[dc + 14][j] = kr3.z; KP[dc + 15][j] = kr3.w;
        *(float4*)&Vs[j][dc + 0]  = vr0;
        *(float4*)&Vs[j][dc + 4]  = vr1;
        *(float4*)&Vs[j][dc + 8]  = vr2;
        *(float4*)&Vs[j][dc + 12] = vr3;
        __syncthreads();

        if (kt + 64 < S_) {
            const float* ks = kb + (size_t)(kt + 64 + j) * 64 + dc;
            const float* vs = vb + (size_t)(kt + 64 + j) * 64 + dc;
            kr0 = *(const float4*)(ks + 0);  kr1 = *(const float4*)(ks + 4);
            kr2 = *(const float4*)(ks + 8);  kr3 = *(const float4*)(ks + 12);
            vr0 = *(const float4*)(vs + 0);  vr1 = *(const float4*)(vs + 4);
            vr2 = *(const float4*)(vs + 8);  vr3 = *(const float4*)(vs + 12);
        }

        float s[4][4] = {};
        #pragma unroll 8
        for (int d = 0; d < 64; ++d) {
            const float4 q4 = *(const float4*)&Qs[d][ty * 4];
            const float4 k4 = *(const float4*)&KP[d][tx * 4];
            s[0][0] = fmaf(q4.x, k4.x, s[0][0]); s[0][1] = fmaf(q4.x, k4.y, s[0][1]);
            s[0][2] = fmaf(q4.x, k4.z, s[0][2]); s[0][3] = fmaf(q4.x, k4.w, s[0][3]);
            s[1][0] = fmaf(q4.y, k4.x, s[1][0]); s[1][1] = fmaf(q4.y, k4.y, s[1][1]);
            s[1][2] = fmaf(q4.y, k4.z, s[1][2]); s[1][3] = fmaf(q4.y, k4.w, s[1][3]);
            s[2][0] = fmaf(q4.z, k4.x, s[2][0]); s[2][1] = fmaf(q4.z, k4.y, s[2][1]);
            s[2][2] = fmaf(q4.z, k4.z, s[2][2]); s[2][3] = fmaf(q4.z, k4.w, s[2][3]);
            s[3][0] = fmaf(q4.w, k4.x, s[3][0]); s[3][1] = fmaf(q4.w, k4.y, s[3][1]);
            s[3][2] = fmaf(q4.w, k4.z, s[3][2]); s[3][3] = fmaf(q4.w, k4.w, s[3][3]);
        }

        float4 prow[4];
        #pragma unroll
        for (int r = 0; r < 4; ++r) {
            float s0 = s[r][0] * 0.125f, s1 = s[r][1] * 0.125f;
            float s2 = s[r][2] * 0.125f, s3 = s[r][3] * 0.125f;
            float rm = fmaxf(fmaxf(s0, s1), fmaxf(s2, s3));
            #pragma unroll
            for (int sh = 1; sh < 16; sh <<= 1) rm = fmaxf(rm, __shfl_xor(rm, sh, 64));
            const float mn = fmaxf(mrow[r], rm);
            const float p0 = expf(s0 - mn), p1 = expf(s1 - mn);
            const float p2 = expf(s2 - mn), p3 = expf(s3 - mn);
            float rs = p0 + p1 + p2 + p3;
            #pragma unroll
            for (int sh = 1; sh < 16; sh <<= 1) rs += __shfl_xor(rs, sh, 64);
            const float esc = expf(mrow[r] - mn);
            lrow[r] = lrow[r] * esc + rs;
            mrow[r] = mn;
            acc[r][0] *= esc; acc[r][1] *= esc; acc[r][2] *= esc; acc[r][3] *= esc;
            prow[r] = make_float4(p0, p1, p2, p3);
        }
        __syncthreads();
        #pragma unroll
        for (int r = 0; r < 4; ++r)
            *(float4*)&KP[ty * 4 + r][tx * 4] = prow[r];
        __syncthreads();

        #pragma unroll 4
        for (int jb = 0; jb < 16; ++jb) {
            const float4 v0 = *(const float4*)&Vs[jb * 4 + 0][tx * 4];
            const float4 v1 = *(const float4*)&Vs[jb * 4 + 1][tx * 4];
            const float4 v2 = *(const float4*)&Vs[jb * 4 + 2][tx * 4];
            const float4 v3 = *(const float4*)&Vs[jb * 4 + 3][tx * 4];
            #pragma unroll
            for (int r = 0; r < 4; ++r) {
                const float4 p4 = *(const float4*)&KP[ty * 4 + r][jb * 4];
                acc[r][0] = fmaf(p4.x, v0.x, acc[r][0]); acc[r][1] = fmaf(p4.x, v0.y, acc[r][1]);
                acc[r][2] = fmaf(p4.x, v0.z, acc[r][2]); acc[r][3] = fmaf(p4.x, v0.w, acc[r][3]);
                acc[r][0] = fmaf(p4.y, v1.x, acc[r][0]); acc[r][1] = fmaf(p4.y, v1.y, acc[r][1]);
                acc[r][2] = fmaf(p4.y, v1.z, acc[r][2]); acc[r][3] = fmaf(p4.y, v1.w, acc[r][3]);
                acc[r][0] = fmaf(p4.z, v2.x, acc[r][0]); acc[r][1] = fmaf(p4.z, v2.y, acc[r][1]);
                acc[r][2] = fmaf(p4.z, v2.z, acc[r][2]); acc[r][3] = fmaf(p4.z, v2.w, acc[r][3]);
                acc[r][0] = fmaf(p4.w, v3.x, acc[r][0]); acc[r][1] = fmaf(p4.w, v3.y, acc[r][1]);
                acc[r][2] = fmaf(p4.w, v3.z, acc[r][2]); acc[r][3] = fmaf(p4.w, v3.w, acc[r][3]);
            }
        }
    }

    const int bb = bh >> 4, hh = bh & 15;
    #pragma unroll
    for (int r = 0; r < 4; ++r) {
        const float inv = 1.0f / lrow[r];
        *(float4*)(ctx + (size_t)(bb * S_ + q0 + ty * 4 + r) * D_ + hh * 64 + tx * 4) =
            make_float4(acc[r][0] * inv, acc[r][1] * inv, acc[r][2] * inv, acc[r][3] * inv);
    }
}

// ---------------- path gate ----------------
__global__ __launch_bounds__(256)
void pathw_k(const float* __restrict__ normed, const float* __restrict__ ctx,
             const float* __restrict__ wp, const float* __restrict__ bp,
             float* __restrict__ pw)
{
    const int m = blockIdx.x, tid = threadIdx.x;
    const float4 n4 = *(const float4*)(normed + (size_t)m * D_ + tid * 4);
    const float4 c4 = *(const float4*)(ctx + (size_t)m * D_ + tid * 4);
    const float4 w0n = *(const float4*)(wp + tid * 4);
    const float4 w0c = *(const float4*)(wp + 1024 + tid * 4);
    const float4 w1n = *(const float4*)(wp + 2048 + tid * 4);
    const float4 w1c = *(const float4*)(wp + 3072 + tid * 4);
    float p0 = n4.x * w0n.x + n4.y * w0n.y + n4.z * w0n.z + n4.w * w0n.w
             + c4.x * w0c.x + c4.y * w0c.y + c4.z * w0c.z + c4.w * w0c.w;
    float p1 = n4.x * w1n.x + n4.y * w1n.y + n4.z * w1n.z + n4.w * w1n.w
             + c4.x * w1c.x + c4.y * w1c.y + c4.z * w1c.z + c4.w * w1c.w;
    p0 = blockReduceSum(p0);
    p1 = blockReduceSum(p1);
    if (tid == 0) {
        const float l0 = p0 + bp[0], l1 = p1 + bp[1];
        const float mx = fmaxf(l0, l1);
        const float e0 = expf(l0 - mx), e1 = expf(l1 - mx);
        const float inv = 1.0f / (e0 + e1);
        pw[2 * m] = e0 * inv;
        pw[2 * m + 1] = e1 * inv;
    }
}

// ---------------- fused router tail: top-16 + router + LN2 + pattern ---------
// Top-k block copied verbatim from the verified topk_router_k.
__global__ __launch_bounds__(256)
void router_tail_k(const float* __restrict__ scores, const float* __restrict__ neurons,
                   const float* __restrict__ x, const float* __restrict__ ln2g,
                   const float* __restrict__ ln2b, const float* __restrict__ pq,
                   const float* __restrict__ gates, float* __restrict__ idx_out,
                   float* __restrict__ x1, unsigned short* __restrict__ normed2bf,
                   unsigned short* __restrict__ gate_out)
{
    __shared__ __align__(16) float sc[4096];
    __shared__ unsigned long long wred[4];
    __shared__ int ki_s[16];
    __shared__ float kv_s[16];
    __shared__ float kw_s[16];
    __shared__ float ps[64];
    __shared__ int pidx[8];
    __shared__ float pwt[8];
    const int m = blockIdx.x, tid = threadIdx.x;
    const float* srow = scores + (size_t)m * 4096;
    for (int i = tid; i < 1024; i += 256)
        *(float4*)&sc[i * 4] = *(const float4*)(srow + i * 4);
    __syncthreads();

    for (int t = 0; t < 16; ++t) {
        unsigned long long best = 0ull;
        for (int i = tid; i < 4096; i += 256) {
            unsigned u = __float_as_uint(sc[i]);
            u = (u & 0x80000000u) ? ~u : (u | 0x80000000u);
            const unsigned long long key =
                ((unsigned long long)u << 32) | (unsigned long long)(0xFFFFFFFFu - (unsigned)i);
            if (key > best) best = key;
        }
        #pragma unroll
        for (int sh = 1; sh < 64; sh <<= 1) {
            const unsigned long long o = __shfl_xor(best, sh, 64);
            if (o > best) best = o;
        }
        if ((tid & 63) == 0) wred[tid >> 6] = best;
        __syncthreads();
        if (tid == 0) {
            unsigned long long bb = wred[0];
            if (wred[1] > bb) bb = wred[1];
            if (wred[2] > bb) bb = wred[2];
            if (wred[3] > bb) bb = wred[3];
            const int idx = (int)(0xFFFFFFFFu - (unsigned)(bb & 0xFFFFFFFFull));
            ki_s[t] = idx;
            kv_s[t] = sc[idx];
            sc[idx] = -INFINITY;
        }
        __syncthreads();
    }

    if (tid == 0) {
        const float mx = kv_s[0];
        float es[16], sum = 0.f;
        #pragma unroll
        for (int t = 0; t < 16; ++t) { es[t] = expf(kv_s[t] - mx); sum += es[t]; }
        const float inv = 1.0f / sum;
        #pragma unroll
        for (int t = 0; t < 16; ++t) kw_s[t] = es[t] * inv;
    }
    __syncthreads();

    if (tid < 16) idx_out[(size_t)m * 16 + tid] = (float)ki_s[tid];

    float4 r = make_float4(0.f, 0.f, 0.f, 0.f);
    #pragma unroll
    for (int t = 0; t < 16; ++t) {
        const float w = kw_s[t];
        const float4 nv = *(const float4*)(neurons + (size_t)ki_s[t] * D_ + tid * 4);
        r.x = fmaf(w, nv.x, r.x); r.y = fmaf(w, nv.y, r.y);
        r.z = fmaf(w, nv.z, r.z); r.w = fmaf(w, nv.w, r.w);
    }
    const float4 xv = *(const float4*)(x + (size_t)m * D_ + tid * 4);
    const float x0 = xv.x + r.x, x1v = xv.y + r.y, x2 = xv.z + r.z, x3 = xv.w + r.w;
    *(float4*)(x1 + (size_t)m * D_ + tid * 4) = make_float4(x0, x1v, x2, x3);

    // ---- LN2 (same formula as ln_k, bf16 out) ----
    {
        float s = x0 + x1v + x2 + x3;
        s = blockReduceSum(s);
        const float mu = s * (1.0f / 1024.0f);
        const float d0 = x0 - mu, d1 = x1v - mu, d2 = x2 - mu, d3 = x3 - mu;
        float sq = d0 * d0 + d1 * d1 + d2 * d2 + d3 * d3;
        sq = blockReduceSum(sq);
        const float rstd = rsqrtf(sq * (1.0f / 1024.0f) + 1e-5f);
        const float4 gv = *(const float4*)(ln2g + tid * 4);
        const float4 bv = *(const float4*)(ln2b + tid * 4);
        unsigned short* ob = normed2bf + (size_t)m * D_ + tid * 4;
        *(ushort4*)ob = make_ushort4(f2bf(d0 * rstd * gv.x + bv.x),
                                     f2bf(d1 * rstd * gv.y + bv.y),
                                     f2bf(d2 * rstd * gv.z + bv.z),
                                     f2bf(d3 * rstd * gv.w + bv.w));
    }

    // ---- pattern: stage router row into sc[0..1023] (dead after top-k) ----
    __syncthreads();
    *(float4*)&sc[tid * 4] = r;
    __syncthreads();

    const int p = tid >> 2, part = tid & 3;
    const float* pqr = pq + (size_t)p * D_ + part * 256;
    float sum = 0.f;
    for (int d = 0; d < 256; d += 4) {
        const float4 a = *(const float4*)(pqr + d);
        const float4 b = *(const float4*)&sc[part * 256 + d];
        sum += a.x * b.x + a.y * b.y + a.z * b.z + a.w * b.w;
    }
    sum += __shfl_xor(sum, 1, 64);
    sum += __shfl_xor(sum, 2, 64);
    if (part == 0) ps[p] = sum * (1.0f / 32.0f);
    __syncthreads();

    if (tid == 0) {
        float kv[8];
        for (int t = 0; t < 8; ++t) {
            float bv = -INFINITY; int bi = 0;
            for (int i = 0; i < 64; ++i) {
                const float vv = ps[i];
                if (vv > bv) { bv = vv; bi = i; }
            }
            kv[t] = bv; pidx[t] = bi; ps[bi] = -INFINITY;
        }
        const float mx = kv[0];
        float ee[8], tot = 0.f;
        for (int t = 0; t < 8; ++t) { ee[t] = expf(kv[t] - mx); tot += ee[t]; }
        for (int t = 0; t < 8; ++t) pwt[t] = ee[t] / tot;
    }
    __syncthreads();

    for (int f = tid * 4; f < 4096; f += 1024) {
        float4 g = make_float4(0.f, 0.f, 0.f, 0.f);
        #pragma unroll
        for (int t = 0; t < 8; ++t) {
            const float w = pwt[t];
            const float4 gv = *(const float4*)(gates + (size_t)pidx[t] * 4096 + f);
            g.x = fmaf(w, gv.x, g.x); g.y = fmaf(w, gv.y, g.y);
            g.z = fmaf(w, gv.z, g.z); g.w = fmaf(w, gv.w, g.w);
        }
        *(ushort4*)(gate_out + (size_t)m * 4096 + f) =
            make_ushort4(f2bf(g.x), f2bf(g.y), f2bf(g.z), f2bf(g.w));
    }
}

// ---------------- fp32 -> bf16 cast (both FFN weights, one dispatch) ---------
__global__ __launch_bounds__(256)
void castbf2_k(const float* __restrict__ a, const float* __restrict__ b,
               unsigned short* __restrict__ oa, unsigned short* __restrict__ ob)
{
    int i = (blockIdx.x * 256 + threadIdx.x) * 8;
    const float* src;
    unsigned short* dst;
    if (i < 4194304) { src = a + i; dst = oa + i; }
    else { src = b + (i - 4194304); dst = ob + (i - 4194304); }
    const float4 u = *(const float4*)(src);
    const float4 v = *(const float4*)(src + 4);
    *(ushort4*)(dst) = make_ushort4(f2bf(u.x), f2bf(u.y), f2bf(u.z), f2bf(u.w));
    *(ushort4*)(dst + 4) = make_ushort4(f2bf(v.x), f2bf(v.y), f2bf(v.z), f2bf(v.w));
}

// ---------------- bf16 MFMA GEMM (round-7 source, verified) ------------------
template<int EPI>
__global__ __launch_bounds__(256)
void gemmbf_k(const unsigned short* __restrict__ A, const unsigned short* __restrict__ Bw,
              const float* __restrict__ bias, const unsigned short* __restrict__ gate,
              const float* resid, void* Cout, int M, int N, int Kd)
{
    constexpr int LSH = 40;
    __shared__ __align__(16) unsigned short Al[128 * LSH];
    __shared__ __align__(16) unsigned short Bl[128 * LSH];
    const int tid = threadIdx.x;
    const int lane = tid & 63;
    const int w = tid >> 6, wr = w >> 1, wc = w & 1;
    const int swz = xcd_swizzle(blockIdx.y * gridDim.x + blockIdx.x,
                                gridDim.x * gridDim.y);
    const int row0 = (swz / gridDim.x) * 128, col0 = (swz % gridDim.x) * 128;

    const int o0 = tid * 16, o1 = o0 + 4096;
    const int r0 = o0 >> 6, k0e = (o0 & 63) >> 1;
    const int r1 = o1 >> 6, k1e = (o1 & 63) >> 1;
    const int l0 = r0 * LSH + k0e, l1 = r1 * LSH + k1e;
    const unsigned short* Ap0 = A + (size_t)(row0 + r0) * Kd + k0e;
    const unsigned short* Ap1 = A + (size_t)(row0 + r1) * Kd + k1e;
    const unsigned short* Bp0 = Bw + (size_t)(col0 + r0) * Kd + k0e;
    const unsigned short* Bp1 = Bw + (size_t)(col0 + r1) * Kd + k1e;

    f32x4 acc[4][4];
    #pragma unroll
    for (int m = 0; m < 4; ++m)
        #pragma unroll
        for (int n = 0; n < 4; ++n)
            #pragma unroll
            for (int e = 0; e < 4; ++e) acc[m][n][e] = 0.f;

    s16x8 ra0 = *(const s16x8*)Ap0;
    s16x8 ra1 = *(const s16x8*)Ap1;
    s16x8 rb0 = *(const s16x8*)Bp0;
    s16x8 rb1 = *(const s16x8*)Bp1;

    const int fr = lane & 15, kg = (lane >> 4) * 8;
    const unsigned short* aBase = Al + ((wr * 64 + fr) * LSH + kg);
    const unsigned short* bBase = Bl + ((wc * 64 + fr) * LSH + kg);

    for (int k0 = 0; k0 < Kd; k0 += 32) {
        __syncthreads();
        *(s16x8*)(Al + l0) = ra0;
        *(s16x8*)(Al + l1) = ra1;
        *(s16x8*)(Bl + l0) = rb0;
        *(s16x8*)(Bl + l1) = rb1;
        __syncthreads();
        if (k0 + 32 < Kd) {
            ra0 = *(const s16x8*)(Ap0 + k0 + 32);
            ra1 = *(const s16x8*)(Ap1 + k0 + 32);
            rb0 = *(const s16x8*)(Bp0 + k0 + 32);
            rb1 = *(const s16x8*)(Bp1 + k0 + 32);
        }
        bf16x8 aF[4], bF[4];
        #pragma unroll
        for (int m = 0; m < 4; ++m) aF[m] = *(const bf16x8*)(aBase + m * 16 * LSH);
        #pragma unroll
        for (int n = 0; n < 4; ++n) bF[n] = *(const bf16x8*)(bBase + n * 16 * LSH);
        #pragma unroll
        for (int m = 0; m < 4; ++m)
            #pragma unroll
            for (int n = 0; n < 4; ++n)
                acc[m][n] = __builtin_amdgcn_mfma_f32_16x16x32_bf16(aF[m], bF[n], acc[m][n], 0, 0, 0);
    }

    const int rbase = (lane >> 4) * 4;
    #pragma unroll
    for (int m = 0; m < 4; ++m) {
        #pragma unroll
        for (int n = 0; n < 4; ++n) {
            const int gcol = col0 + wc * 64 + n * 16 + (lane & 15);
            const int growb = row0 + wr * 64 + m * 16 + rbase;
            const float bc = bias[gcol];
            #pragma unroll
            for (int r = 0; r < 4; ++r) {
                const int grow = growb + r;
                const float vv = acc[m][n][r];
                if constexpr (EPI == 0) {
                    const float z = vv + bc;
                    const float gt = bf2f(gate[(size_t)grow * N + gcol]);
                    const float zz = z / (1.f + expf(-gt));
                    const float o = 0.5f * zz * (1.f + erff(zz * 0.70710678118654752440f));
                    ((unsigned short*)Cout)[(size_t)grow * N + gcol] = f2bf(o);
                } else {
                    ((float*)Cout)[(size_t)grow * N + gcol] =
                        vv + bc + resid[(size_t)grow * N + gcol];
                }
            }
        }
    }
}

// ---------------- launcher ----------------
extern "C" void kernel_launch(void* const* d_in, const int* in_sizes, int n_in,
                              void* d_out, int out_size, void* d_ws, size_t ws_size,
                              hipStream_t stream)
{
    const float* x      = (const float*)d_in[0];
    const float* neurons= (const float*)d_in[1];
    const float* wq = (const float*)d_in[2];  const float* bq = (const float*)d_in[3];
    const float* wk = (const float*)d_in[4];  const float* bk = (const float*)d_in[5];
    const float* wv = (const float*)d_in[6];  const float* bv = (const float*)d_in[7];
    const float* wp = (const float*)d_in[8];  const float* bp = (const float*)d_in[9];
    const float* pq = (const float*)d_in[10];
    const float* gates = (const float*)d_in[11];
    const float* w_up = (const float*)d_in[12];  const float* b_up = (const float*)d_in[13];
    const float* w_dn = (const float*)d_in[14];  const float* b_dn = (const float*)d_in[15];
    const float* ln1g = (const float*)d_in[16];  const float* ln1b = (const float*)d_in[17];
    const float* ln2g = (const float*)d_in[18];  const float* ln2b = (const float*)d_in[19];

    float* out0    = (float*)d_out;
    float* idx_out = out0 + (size_t)4096 * 1024;

    float* ws      = (float*)d_ws;
    float* scores  = ws;                 // 16,777,216 floats
    float* normed  = ws + 16777216;      //  4,194,304
    float* qb      = ws + 20971520;      //  4,194,304 (qkv base)
    float* kb      = ws + 25165824;      //  4,194,304
    float* vb      = ws + 29360128;      //  4,194,304
    float* ctx     = ws + 33554432;      //  4,194,304
    float* router  = ws + 37748736;      //  4,194,304
    float* pw      = ws + 41943040;      //      8,192

    unsigned short* gate_bf   = (unsigned short*)qb;   // qb+kb regions (32 MB), dead after attn
    unsigned short* normed2bf = (unsigned short*)vb;   // vb region (8 MB used), dead after attn
    unsigned short* h_bf      = (unsigned short*)scores;  // scores[0..8.4M floats)
    unsigned short* wup_bf    = (unsigned short*)router;  // router region now weights-only
    unsigned short* wdn_bf    = wup_bf + 4194304;
    float* x1 = out0;

    const dim3 blk(256);

    ln_k<<<4096, blk, 0, stream>>>(x, ln1g, ln1b, normed);
    gemmqkv_k<<<dim3(24, 32), blk, 0, stream>>>(normed, wq, wk, wv, bq, bk, bv, qb);
    attn4_k<<<dim3(32, 32), blk, 0, stream>>>(qb, kb, vb, ctx);
    pathw_k<<<4096, blk, 0, stream>>>(normed, ctx, wp, bp, pw);
    gemm32_k<2><<<dim3(32, 32), blk, 0, stream>>>(normed, neurons, nullptr, pw, scores, 4096, 4096, 1024);
    gemm32_k<3><<<dim3(32, 32), blk, 0, stream>>>(ctx, neurons, nullptr, pw + 1, scores, 4096, 4096, 1024);
    router_tail_k<<<4096, blk, 0, stream>>>(scores, neurons, x, ln2g, ln2b, pq, gates,
                                            idx_out, x1, normed2bf, gate_bf);
    castbf2_k<<<4096, blk, 0, stream>>>(w_up, w_dn, wup_bf, wdn_bf);
    gemmbf_k<0><<<dim3(32, 32), blk, 0, stream>>>(normed2bf, wup_bf, b_up, gate_bf, nullptr, h_bf, 4096, 4096, 1024);
    gemmbf_k<1><<<dim3(8, 32), blk, 0, stream>>>(h_bf, wdn_bf, b_dn, nullptr, x1, out0, 4096, 1024, 4096);
}